// Round 5
// baseline (435.115 us; speedup 1.0000x reference)
//
#include <hip/hip_runtime.h>

// Problem constants (B,N,M,D) = (16,1024,4096,256), all fp32.
constexpr int B_ = 16, N_ = 1024, M_ = 4096, D_ = 256;
constexpr int ROWS = B_ * N_;      // 16384 query rows
constexpr int BR = 128;            // rows per block
constexpr int BC = 128;            // cols per tile
constexpr int KC = 16;             // K chunk
constexpr int CS = 8;              // column splits
constexpr int CPS = M_ / CS;       // cols per split = 512
constexpr int LDP = 132;           // padded LDS leading dim

// ---------------------------------------------------------------------------
// Kernel 1: row sum-of-squares replicating numpy pairwise_sum bit-exactly for
// n=256 contiguous fp32 (two 128-blocks, 8 stride-8 accumulators each).
// ---------------------------------------------------------------------------
__global__ void rowsq_kernel(const float* __restrict__ E, const float* __restrict__ T,
                             float* __restrict__ esq, float* __restrict__ tsq) {
    int gt = blockIdx.x * blockDim.x + threadIdx.x;
    int row = gt >> 4;
    int l = gt & 15;
    if (row >= ROWS + M_) return;
    const float* src = (row < ROWS) ? (E + (size_t)row * D_)
                                    : (T + (size_t)(row - ROWS) * D_);
    const float* p = src + (l >> 3) * 128 + (l & 7);
    float r = __fmul_rn(p[0], p[0]);
    #pragma unroll
    for (int i = 1; i < 16; i++) {
        float x = p[8 * i];
        r = __fadd_rn(r, __fmul_rn(x, x));
    }
    float u = __fadd_rn(r, __shfl_xor(r, 1, 64));
    float v = __fadd_rn(u, __shfl_xor(u, 2, 64));
    float w = __fadd_rn(v, __shfl_xor(v, 4, 64));
    float s = __fadd_rn(w, __shfl_xor(w, 8, 64));
    if (l == 0) {
        if (row < ROWS) esq[row] = s;
        else            tsq[row - ROWS] = s;
    }
}

// ---------------------------------------------------------------------------
// Kernel 2: fused GEMM (cross = E . T^T) + running argmin of the reference's
// fp32-quantized distance d2 = fl(fl(e_sq - 2*cross) + t_sq).
// NUMERICS FROZEN vs round-3 (passed absmax=0): per-(r,c) fmaf chain over
// k = 0..255 ascending, identical epilogue rounding, min-index ties.
// NEW: double-buffered LDS + register prefetch one chunk ahead; ONE barrier
// per chunk: ds_write(i) -> barrier -> issue loads(i+1) -> compute(i).
// Safety: a wave reaching writes(i+2) passed a barrier all waves reached
// only after completing compute(i)'s reads of that same buffer.
// ---------------------------------------------------------------------------
__global__ __launch_bounds__(256) void score_kernel(
    const float* __restrict__ E, const float* __restrict__ T,
    const float* __restrict__ esq, const float* __restrict__ tsq,
    float2* __restrict__ part) {
    __shared__ float Es[2][KC][LDP];
    __shared__ float Ts[2][KC][LDP];
    const int tid = threadIdx.x;
    const int tx = tid & 15;
    const int ty = tid >> 4;
    const int row0 = blockIdx.x * BR;
    const int cs = blockIdx.y;

    float best[8];
    int   bidx[8];
    float er[8];
    #pragma unroll
    for (int r = 0; r < 8; r++) {
        best[r] = 3.4e38f; bidx[r] = 0;
        er[r] = esq[row0 + ty * 8 + r];
    }

    const int ldr = tid >> 2;        // 0..63
    const int ldk = (tid & 3) * 4;   // 0,4,8,12

    const float* Ea = E + (size_t)(row0 + ldr) * D_ + ldk;
    const float* Eb = E + (size_t)(row0 + ldr + 64) * D_ + ldk;

    // Preload chunk (ct=0, k0=0)
    float4 a0, a1, b0, b1;
    {
        const int col0 = cs * CPS;
        a0 = *reinterpret_cast<const float4*>(Ea);
        a1 = *reinterpret_cast<const float4*>(Eb);
        b0 = *reinterpret_cast<const float4*>(T + (size_t)(col0 + ldr     ) * D_ + ldk);
        b1 = *reinterpret_cast<const float4*>(T + (size_t)(col0 + ldr + 64) * D_ + ldk);
    }

    int buf = 0;
    for (int ct = 0; ct < CPS / BC; ++ct) {
        const int col0 = cs * CPS + ct * BC;
        float acc[8][8];
        #pragma unroll
        for (int r = 0; r < 8; r++)
            #pragma unroll
            for (int c = 0; c < 8; c++) acc[r][c] = 0.f;

        for (int k0 = 0; k0 < D_; k0 += KC) {
            // Stage current chunk (in regs) into LDS buffer `buf`, transposed.
            Es[buf][ldk + 0][ldr] = a0.x; Es[buf][ldk + 1][ldr] = a0.y;
            Es[buf][ldk + 2][ldr] = a0.z; Es[buf][ldk + 3][ldr] = a0.w;
            Es[buf][ldk + 0][ldr + 64] = a1.x; Es[buf][ldk + 1][ldr + 64] = a1.y;
            Es[buf][ldk + 2][ldr + 64] = a1.z; Es[buf][ldk + 3][ldr + 64] = a1.w;
            Ts[buf][ldk + 0][ldr] = b0.x; Ts[buf][ldk + 1][ldr] = b0.y;
            Ts[buf][ldk + 2][ldr] = b0.z; Ts[buf][ldk + 3][ldr] = b0.w;
            Ts[buf][ldk + 0][ldr + 64] = b1.x; Ts[buf][ldk + 1][ldr + 64] = b1.y;
            Ts[buf][ldk + 2][ldr + 64] = b1.z; Ts[buf][ldk + 3][ldr + 64] = b1.w;
            __syncthreads();

            // Issue next chunk's global loads; latency hides under compute.
            if (!(ct == CPS / BC - 1 && k0 == D_ - KC)) {
                const int nct  = (k0 == D_ - KC) ? ct + 1 : ct;
                const int nk0  = (k0 == D_ - KC) ? 0 : k0 + KC;
                const int ncol = cs * CPS + nct * BC;
                a0 = *reinterpret_cast<const float4*>(Ea + nk0);
                a1 = *reinterpret_cast<const float4*>(Eb + nk0);
                b0 = *reinterpret_cast<const float4*>(T + (size_t)(ncol + ldr     ) * D_ + nk0 + ldk);
                b1 = *reinterpret_cast<const float4*>(T + (size_t)(ncol + ldr + 64) * D_ + nk0 + ldk);
            }

            // Compute chunk from buffer `buf` (fmaf chain order identical).
            #pragma unroll
            for (int k = 0; k < KC; k++) {
                float e[8], t[8];
                *reinterpret_cast<float4*>(&e[0]) = *reinterpret_cast<const float4*>(&Es[buf][k][ty * 8]);
                *reinterpret_cast<float4*>(&e[4]) = *reinterpret_cast<const float4*>(&Es[buf][k][ty * 8 + 4]);
                *reinterpret_cast<float4*>(&t[0]) = *reinterpret_cast<const float4*>(&Ts[buf][k][tx * 4]);
                *reinterpret_cast<float4*>(&t[4]) = *reinterpret_cast<const float4*>(&Ts[buf][k][64 + tx * 4]);
                #pragma unroll
                for (int r = 0; r < 8; r++)
                    #pragma unroll
                    for (int c = 0; c < 8; c++)
                        acc[r][c] = fmaf(e[r], t[c], acc[r][c]);
            }
            buf ^= 1;
        }
        // Epilogue: d2 = fl(fl(esq - 2*cross) + tsq); running argmin.
        #pragma unroll
        for (int g = 0; g < 2; g++)
            #pragma unroll
            for (int c = 0; c < 4; c++) {
                const int col = col0 + g * 64 + tx * 4 + c;
                const float tc = tsq[col];
                #pragma unroll
                for (int r = 0; r < 8; r++) {
                    const float d1 = __fsub_rn(er[r], __fmul_rn(2.0f, acc[r][g * 4 + c]));
                    const float d2 = __fadd_rn(d1, tc);
                    if (d2 < best[r]) { best[r] = d2; bidx[r] = col; }
                }
            }
    }

    // Reduce across the 16 tx lanes of each ty group; min value, min index on tie.
    #pragma unroll
    for (int r = 0; r < 8; r++) {
        float v = best[r]; int i = bidx[r];
        #pragma unroll
        for (int off = 1; off < 16; off <<= 1) {
            float ov = __shfl_xor(v, off, 64);
            int   oi = __shfl_xor(i, off, 64);
            if (ov < v || (ov == v && oi < i)) { v = ov; i = oi; }
        }
        if (tx == 0)
            part[(size_t)(row0 + ty * 8 + r) * CS + cs] = make_float2(v, __int_as_float(i));
    }
}

// ---------------------------------------------------------------------------
// Kernel 3: reduce CS partials per row (min value, min index on ties), gather
// quant = templat[idx] (bitwise copy), write zidx as float. One wave per row.
// ---------------------------------------------------------------------------
__global__ void gather_kernel(const float* __restrict__ T, const float2* __restrict__ part,
                              float* __restrict__ quant, float* __restrict__ zout) {
    int gt = blockIdx.x * blockDim.x + threadIdx.x;
    int w = gt >> 6, lane = gt & 63;
    if (w >= ROWS) return;
    float2 p = part[(size_t)w * CS];
    float v = p.x; int idx = __float_as_int(p.y);
    #pragma unroll
    for (int c = 1; c < CS; c++) {
        float2 q = part[(size_t)w * CS + c];
        int qi = __float_as_int(q.y);
        if (q.x < v || (q.x == v && qi < idx)) { v = q.x; idx = qi; }
    }
    float4 t = *reinterpret_cast<const float4*>(T + (size_t)idx * D_ + lane * 4);
    *reinterpret_cast<float4*>(quant + (size_t)w * D_ + lane * 4) = t;
    if (lane == 0) zout[w] = (float)idx;
}

// ---------------------------------------------------------------------------
extern "C" void kernel_launch(void* const* d_in, const int* in_sizes, int n_in,
                              void* d_out, int out_size, void* d_ws, size_t ws_size,
                              hipStream_t stream) {
    const float* E = (const float*)d_in[0];   // encode  (B,N,D)
    const float* T = (const float*)d_in[1];   // templat (M,D)
    float* quant = (float*)d_out;                        // (B,N,D) fp32
    float* zout  = quant + (size_t)ROWS * D_;            // (B,N) idx as fp32
    float* esq   = (float*)d_ws;                         // ROWS floats
    float* tsq   = esq + ROWS;                           // M floats
    float2* part = (float2*)(tsq + M_);                  // ROWS*CS float2

    hipLaunchKernelGGL(rowsq_kernel, dim3((ROWS + M_) * 16 / 256), dim3(256), 0, stream, E, T, esq, tsq);
    hipLaunchKernelGGL(score_kernel, dim3(ROWS / BR, CS), dim3(256), 0, stream, E, T, esq, tsq, part);
    hipLaunchKernelGGL(gather_kernel, dim3(ROWS * 64 / 256), dim3(256), 0, stream, T, part, quant, zout);
}

// Round 6
// 156.269 us; speedup vs baseline: 2.7844x; 2.7844x over previous
//
#include <hip/hip_runtime.h>

// Problem constants (B,N,M,D) = (16,1024,4096,256), all fp32.
// Strategy: cross-GEMM on matrix cores via exact 2-term fp16 split
// (e = ae+be, t*2^17 = at+bt), 3 MFMA products ae*at + ae*bt + be*at.
// Numerics: cross error ~2e-9 << ulp(256)/2 = 1.5e-5 quantum of the
// reference's d2 = fl(fl(esq - 2*cross) + tsq), and 30x below the fmaf
// reorder noise that passed bitwise in round 3. Epilogue rounding path
// and esq/tsq (np-pairwise bitwise) are FROZEN from the passing kernel.

typedef _Float16 half8 __attribute__((ext_vector_type(8)));
typedef float f32x4 __attribute__((ext_vector_type(4)));

constexpr int B_ = 16, N_ = 1024, M_ = 4096, D_ = 256;
constexpr int ROWS = B_ * N_;      // 16384 query rows
constexpr int BR = 128;            // rows per block
constexpr int BC = 128;            // cols per col-tile
constexpr int NCT = 4;             // col-tiles per block
constexpr int CS = 8;              // col splits (blockIdx.y)
constexpr int CPB = BC * NCT;      // 512 cols per block
constexpr int KC = 32;             // k per chunk = one 16x16x32 MFMA-K
constexpr int LDH = 40;            // LDS row stride in halfs (64B data + 16B pad)
constexpr int NPART = CS * 2;      // 16 partials per row (2 col-half waves)
constexpr float TSCALE = 131072.0f;        // 2^17 (exact)
constexpr float INV2 = 1.52587890625e-05f; // 2^-16: acc*2^-16 == 2*cross, exact

// ---------------------------------------------------------------------------
// Kernel 1 (FROZEN): row sum-of-squares, numpy pairwise bit-exact for n=256.
// ---------------------------------------------------------------------------
__global__ void rowsq_kernel(const float* __restrict__ E, const float* __restrict__ T,
                             float* __restrict__ esq, float* __restrict__ tsq) {
    int gt = blockIdx.x * blockDim.x + threadIdx.x;
    int row = gt >> 4;
    int l = gt & 15;
    if (row >= ROWS + M_) return;
    const float* src = (row < ROWS) ? (E + (size_t)row * D_)
                                    : (T + (size_t)(row - ROWS) * D_);
    const float* p = src + (l >> 3) * 128 + (l & 7);
    float r = __fmul_rn(p[0], p[0]);
    #pragma unroll
    for (int i = 1; i < 16; i++) {
        float x = p[8 * i];
        r = __fadd_rn(r, __fmul_rn(x, x));
    }
    float u = __fadd_rn(r, __shfl_xor(r, 1, 64));
    float v = __fadd_rn(u, __shfl_xor(u, 2, 64));
    float w = __fadd_rn(v, __shfl_xor(v, 4, 64));
    float s = __fadd_rn(w, __shfl_xor(w, 8, 64));
    if (l == 0) {
        if (row < ROWS) esq[row] = s;
        else            tsq[row - ROWS] = s;
    }
}

// ---------------------------------------------------------------------------
// Kernel 2: MFMA fused GEMM + argmin of d2 = fl(fl(esq - 2*cross) + tsq).
// 256 threads = 4 waves (2x2 of 64x64); wave = 4x4 frags of 16x16x32_f16.
// A-frag: lane l holds E[row = f*16 + (l&15)][k = (l>>4)*8 + j], j=0..7.
// B-frag: lane l holds T'[col = f*16 + (l&15)][same k].
// C/D: col = lane&15, row = (lane>>4)*4 + reg  [verified m89].
// LDS: hi/lo tiles, 80B padded rows -> frag reads 2-way bank (free).
// ---------------------------------------------------------------------------
__global__ __launch_bounds__(256) void score_kernel(
    const float* __restrict__ E, const float* __restrict__ T,
    const float* __restrict__ esq, const float* __restrict__ tsq,
    float2* __restrict__ part) {
    __shared__ _Float16 Ehi[BR][LDH];
    __shared__ _Float16 Elo[BR][LDH];
    __shared__ _Float16 Thi[BC][LDH];
    __shared__ _Float16 Tlo[BC][LDH];

    const int tid = threadIdx.x;
    const int w  = tid >> 6;       // wave 0..3
    const int l  = tid & 63;
    const int wr = w >> 1;         // row half (0/1)
    const int wc = w & 1;          // col half (0/1)
    const int q  = l >> 4;         // lane quarter
    const int cl = l & 15;         // col-in-frag
    const int row0 = blockIdx.x * BR;
    const int cs = blockIdx.y;
    const int colB = cs * CPB;

    const int srow  = tid >> 1;         // staging row 0..127
    const int skoff = (tid & 1) * 16;   // staging k offset 0/16

    // Per-lane esq values for the 16 (fr,reg) row slots (reused all ct).
    float er[16];
    #pragma unroll
    for (int fr = 0; fr < 4; fr++)
        #pragma unroll
        for (int rg = 0; rg < 4; rg++)
            er[fr * 4 + rg] = esq[row0 + wr * 64 + fr * 16 + q * 4 + rg];

    float best[16];
    int   bidx[16];
    #pragma unroll
    for (int i = 0; i < 16; i++) { best[i] = 3.4e38f; bidx[i] = 0; }

    for (int ct = 0; ct < NCT; ct++) {
        const int col0 = colB + ct * BC;
        f32x4 acc[4][4];
        #pragma unroll
        for (int i = 0; i < 4; i++)
            #pragma unroll
            for (int j = 0; j < 4; j++)
                acc[i][j] = (f32x4){0.f, 0.f, 0.f, 0.f};

        for (int kc = 0; kc < D_; kc += KC) {
            __syncthreads();   // protect LDS from previous chunk's readers
            // --- stage E chunk: 16 floats/thread -> hi/lo fp16 ---
            {
                const float* src = E + (size_t)(row0 + srow) * D_ + kc + skoff;
                float x[16];
                *reinterpret_cast<float4*>(&x[0])  = *reinterpret_cast<const float4*>(src);
                *reinterpret_cast<float4*>(&x[4])  = *reinterpret_cast<const float4*>(src + 4);
                *reinterpret_cast<float4*>(&x[8])  = *reinterpret_cast<const float4*>(src + 8);
                *reinterpret_cast<float4*>(&x[12]) = *reinterpret_cast<const float4*>(src + 12);
                half8 h0, h1, lo0, lo1;
                #pragma unroll
                for (int j = 0; j < 8; j++) {
                    _Float16 h = (_Float16)x[j];
                    h0[j] = h; lo0[j] = (_Float16)(x[j] - (float)h);
                }
                #pragma unroll
                for (int j = 0; j < 8; j++) {
                    _Float16 h = (_Float16)x[8 + j];
                    h1[j] = h; lo1[j] = (_Float16)(x[8 + j] - (float)h);
                }
                *reinterpret_cast<half8*>(&Ehi[srow][skoff])     = h0;
                *reinterpret_cast<half8*>(&Ehi[srow][skoff + 8]) = h1;
                *reinterpret_cast<half8*>(&Elo[srow][skoff])     = lo0;
                *reinterpret_cast<half8*>(&Elo[srow][skoff + 8]) = lo1;
            }
            // --- stage T chunk scaled by 2^17 (exact) ---
            {
                const float* src = T + (size_t)(col0 + srow) * D_ + kc + skoff;
                float x[16];
                *reinterpret_cast<float4*>(&x[0])  = *reinterpret_cast<const float4*>(src);
                *reinterpret_cast<float4*>(&x[4])  = *reinterpret_cast<const float4*>(src + 4);
                *reinterpret_cast<float4*>(&x[8])  = *reinterpret_cast<const float4*>(src + 8);
                *reinterpret_cast<float4*>(&x[12]) = *reinterpret_cast<const float4*>(src + 12);
                #pragma unroll
                for (int j = 0; j < 16; j++) x[j] *= TSCALE;
                half8 h0, h1, lo0, lo1;
                #pragma unroll
                for (int j = 0; j < 8; j++) {
                    _Float16 h = (_Float16)x[j];
                    h0[j] = h; lo0[j] = (_Float16)(x[j] - (float)h);
                }
                #pragma unroll
                for (int j = 0; j < 8; j++) {
                    _Float16 h = (_Float16)x[8 + j];
                    h1[j] = h; lo1[j] = (_Float16)(x[8 + j] - (float)h);
                }
                *reinterpret_cast<half8*>(&Thi[srow][skoff])     = h0;
                *reinterpret_cast<half8*>(&Thi[srow][skoff + 8]) = h1;
                *reinterpret_cast<half8*>(&Tlo[srow][skoff])     = lo0;
                *reinterpret_cast<half8*>(&Tlo[srow][skoff + 8]) = lo1;
            }
            __syncthreads();

            // --- frags: cache hi-frags, stream lo-frags through tmp ---
            half8 ah[4], bh[4], tmp[4];
            #pragma unroll
            for (int f = 0; f < 4; f++)
                ah[f] = *reinterpret_cast<const half8*>(&Ehi[wr * 64 + f * 16 + cl][q * 8]);
            #pragma unroll
            for (int f = 0; f < 4; f++)
                bh[f] = *reinterpret_cast<const half8*>(&Thi[wc * 64 + f * 16 + cl][q * 8]);
            #pragma unroll
            for (int i = 0; i < 4; i++)
                #pragma unroll
                for (int j = 0; j < 4; j++)
                    acc[i][j] = __builtin_amdgcn_mfma_f32_16x16x32_f16(ah[i], bh[j], acc[i][j], 0, 0, 0);
            #pragma unroll
            for (int f = 0; f < 4; f++)
                tmp[f] = *reinterpret_cast<const half8*>(&Tlo[wc * 64 + f * 16 + cl][q * 8]);
            #pragma unroll
            for (int i = 0; i < 4; i++)
                #pragma unroll
                for (int j = 0; j < 4; j++)
                    acc[i][j] = __builtin_amdgcn_mfma_f32_16x16x32_f16(ah[i], tmp[j], acc[i][j], 0, 0, 0);
            #pragma unroll
            for (int f = 0; f < 4; f++)
                tmp[f] = *reinterpret_cast<const half8*>(&Elo[wr * 64 + f * 16 + cl][q * 8]);
            #pragma unroll
            for (int i = 0; i < 4; i++)
                #pragma unroll
                for (int j = 0; j < 4; j++)
                    acc[i][j] = __builtin_amdgcn_mfma_f32_16x16x32_f16(tmp[i], bh[j], acc[i][j], 0, 0, 0);
        }

        // Epilogue: d2 = fl(fl(er - acc*2^-16) + tc); running argmin.
        // Cols ascend (fc within ct, ct outer) -> strict '<' keeps min index.
        #pragma unroll
        for (int fc = 0; fc < 4; fc++) {
            const int col = col0 + wc * 64 + fc * 16 + cl;
            const float tc = tsq[col];
            #pragma unroll
            for (int fr = 0; fr < 4; fr++)
                #pragma unroll
                for (int rg = 0; rg < 4; rg++) {
                    const float c2 = acc[fr][fc][rg] * INV2;  // exact scale
                    const float d1 = __fsub_rn(er[fr * 4 + rg], c2);
                    const float d2 = __fadd_rn(d1, tc);
                    const int s = fr * 4 + rg;
                    if (d2 < best[s]) { best[s] = d2; bidx[s] = col; }
                }
        }
    }

    // Cross-lane reduce within each 16-lane quarter (same rows, diff cols).
    #pragma unroll
    for (int s = 0; s < 16; s++) {
        float v = best[s]; int i = bidx[s];
        #pragma unroll
        for (int off = 1; off < 16; off <<= 1) {
            float ov = __shfl_xor(v, off, 64);
            int   oi = __shfl_xor(i, off, 64);
            if (ov < v || (ov == v && oi < i)) { v = ov; i = oi; }
        }
        if (cl == 0) {
            const int row = row0 + wr * 64 + (s >> 2) * 16 + q * 4 + (s & 3);
            part[(size_t)row * NPART + cs * 2 + wc] = make_float2(v, __int_as_float(i));
        }
    }
}

// ---------------------------------------------------------------------------
// Kernel 3: reduce NPART partials per row (min value, min index on ties),
// gather quant = templat[idx] (bitwise copy), write zidx as float.
// ---------------------------------------------------------------------------
__global__ void gather_kernel(const float* __restrict__ T, const float2* __restrict__ part,
                              float* __restrict__ quant, float* __restrict__ zout) {
    int gt = blockIdx.x * blockDim.x + threadIdx.x;
    int w = gt >> 6, lane = gt & 63;
    if (w >= ROWS) return;
    float2 p = part[(size_t)w * NPART];
    float v = p.x; int idx = __float_as_int(p.y);
    #pragma unroll
    for (int c = 1; c < NPART; c++) {
        float2 q = part[(size_t)w * NPART + c];
        int qi = __float_as_int(q.y);
        if (q.x < v || (q.x == v && qi < idx)) { v = q.x; idx = qi; }
    }
    float4 t = *reinterpret_cast<const float4*>(T + (size_t)idx * D_ + lane * 4);
    *reinterpret_cast<float4*>(quant + (size_t)w * D_ + lane * 4) = t;
    if (lane == 0) zout[w] = (float)idx;
}

// ---------------------------------------------------------------------------
extern "C" void kernel_launch(void* const* d_in, const int* in_sizes, int n_in,
                              void* d_out, int out_size, void* d_ws, size_t ws_size,
                              hipStream_t stream) {
    const float* E = (const float*)d_in[0];   // encode  (B,N,D)
    const float* T = (const float*)d_in[1];   // templat (M,D)
    float* quant = (float*)d_out;                        // (B,N,D) fp32
    float* zout  = quant + (size_t)ROWS * D_;            // (B,N) idx as fp32
    float* esq   = (float*)d_ws;                         // ROWS floats
    float* tsq   = esq + ROWS;                           // M floats
    float2* part = (float2*)(tsq + M_);                  // ROWS*NPART float2

    hipLaunchKernelGGL(rowsq_kernel, dim3((ROWS + M_) * 16 / 256), dim3(256), 0, stream, E, T, esq, tsq);
    hipLaunchKernelGGL(score_kernel, dim3(ROWS / BR, CS), dim3(256), 0, stream, E, T, esq, tsq, part);
    hipLaunchKernelGGL(gather_kernel, dim3(ROWS * 64 / 256), dim3(256), 0, stream, T, part, quant, zout);
}

// Round 7
// 154.625 us; speedup vs baseline: 2.8140x; 1.0106x over previous
//
#include <hip/hip_runtime.h>

// Problem constants (B,N,M,D) = (16,1024,4096,256), all fp32.
// Strategy: cross-GEMM on matrix cores via exact 2-term fp16 split
// (e = ae+be, t*2^17 = at+bt), 3 MFMA products ae*at + ae*bt + be*at.
// Splits PRECOMPUTED once into ws (round-7 change: removes ~80 VALU/thread/
// chunk of redundant conversion from the hot loop; values bitwise identical).
// Numerics FROZEN from round-6 (passed absmax=0): same MFMA product/k order,
// same epilogue d2 = fl(fl(esq - 2*cross) + tsq), np-pairwise esq/tsq.

typedef _Float16 half8 __attribute__((ext_vector_type(8)));
typedef float f32x4 __attribute__((ext_vector_type(4)));

constexpr int B_ = 16, N_ = 1024, M_ = 4096, D_ = 256;
constexpr int ROWS = B_ * N_;      // 16384 query rows
constexpr int BR = 128;            // rows per block
constexpr int BC = 128;            // cols per col-tile
constexpr int NCT = 4;             // col-tiles per block
constexpr int CS = 8;              // col splits (blockIdx.y)
constexpr int CPB = BC * NCT;      // 512 cols per block
constexpr int KC = 32;             // k per chunk = one 16x16x32 MFMA-K
constexpr int LDH = 40;            // LDS row stride in halfs (64B data + 16B pad)
constexpr int NPART = CS * 2;      // 16 partials per row (2 col-half waves)
constexpr float TSCALE = 131072.0f;        // 2^17 (exact)
constexpr float INV2 = 1.52587890625e-05f; // 2^-16: acc*2^-16 == 2*cross, exact

// ---------------------------------------------------------------------------
// Kernel 0: one-time hi/lo fp16 split of E and T (T scaled by 2^17, exact).
// Memory-bound (~42 MB). One thread per 8 elements.
// ---------------------------------------------------------------------------
__global__ void split_kernel(const float* __restrict__ E, const float* __restrict__ T,
                             _Float16* __restrict__ Ehi, _Float16* __restrict__ Elo,
                             _Float16* __restrict__ Thi, _Float16* __restrict__ Tlo) {
    int idx = blockIdx.x * blockDim.x + threadIdx.x;
    int row = idx >> 5;            // 32 threads per 256-elem row
    int c8 = (idx & 31) * 8;
    if (row >= ROWS + M_) return;
    const float* src;
    _Float16 *hi, *lo;
    size_t off;
    float scale;
    if (row < ROWS) {
        off = (size_t)row * D_ + c8;
        src = E + off; hi = Ehi; lo = Elo; scale = 1.0f;
    } else {
        off = (size_t)(row - ROWS) * D_ + c8;
        src = T + off; hi = Thi; lo = Tlo; scale = TSCALE;
    }
    float x[8];
    *reinterpret_cast<float4*>(&x[0]) = *reinterpret_cast<const float4*>(src);
    *reinterpret_cast<float4*>(&x[4]) = *reinterpret_cast<const float4*>(src + 4);
    half8 h, l;
    #pragma unroll
    for (int j = 0; j < 8; j++) {
        float xs = x[j] * scale;               // exact for T (pow2), 1.0 for E
        _Float16 hh = (_Float16)xs;            // RN, same as round-6 in-loop
        h[j] = hh;
        l[j] = (_Float16)(xs - (float)hh);
    }
    *reinterpret_cast<half8*>(hi + off) = h;
    *reinterpret_cast<half8*>(lo + off) = l;
}

// ---------------------------------------------------------------------------
// Kernel 1 (FROZEN): row sum-of-squares, numpy pairwise bit-exact for n=256.
// ---------------------------------------------------------------------------
__global__ void rowsq_kernel(const float* __restrict__ E, const float* __restrict__ T,
                             float* __restrict__ esq, float* __restrict__ tsq) {
    int gt = blockIdx.x * blockDim.x + threadIdx.x;
    int row = gt >> 4;
    int l = gt & 15;
    if (row >= ROWS + M_) return;
    const float* src = (row < ROWS) ? (E + (size_t)row * D_)
                                    : (T + (size_t)(row - ROWS) * D_);
    const float* p = src + (l >> 3) * 128 + (l & 7);
    float r = __fmul_rn(p[0], p[0]);
    #pragma unroll
    for (int i = 1; i < 16; i++) {
        float x = p[8 * i];
        r = __fadd_rn(r, __fmul_rn(x, x));
    }
    float u = __fadd_rn(r, __shfl_xor(r, 1, 64));
    float v = __fadd_rn(u, __shfl_xor(u, 2, 64));
    float w = __fadd_rn(v, __shfl_xor(v, 4, 64));
    float s = __fadd_rn(w, __shfl_xor(w, 8, 64));
    if (l == 0) {
        if (row < ROWS) esq[row] = s;
        else            tsq[row - ROWS] = s;
    }
}

// ---------------------------------------------------------------------------
// Kernel 2: MFMA fused GEMM + argmin of d2 = fl(fl(esq - 2*cross) + tsq).
// 256 threads = 4 waves (2x2 of 64x64); wave = 4x4 frags of 16x16x32_f16.
// Staging is now pure fp16 loads (32B/thread/array) -> LDS; no conversions.
// ---------------------------------------------------------------------------
__global__ __launch_bounds__(256) void score_kernel(
    const _Float16* __restrict__ Ehi_g, const _Float16* __restrict__ Elo_g,
    const _Float16* __restrict__ Thi_g, const _Float16* __restrict__ Tlo_g,
    const float* __restrict__ esq, const float* __restrict__ tsq,
    float2* __restrict__ part) {
    __shared__ _Float16 Ehi[BR][LDH];
    __shared__ _Float16 Elo[BR][LDH];
    __shared__ _Float16 Thi[BC][LDH];
    __shared__ _Float16 Tlo[BC][LDH];

    const int tid = threadIdx.x;
    const int w  = tid >> 6;       // wave 0..3
    const int l  = tid & 63;
    const int wr = w >> 1;         // row half (0/1)
    const int wc = w & 1;          // col half (0/1)
    const int q  = l >> 4;         // lane quarter
    const int cl = l & 15;         // col-in-frag
    const int row0 = blockIdx.x * BR;
    const int cs = blockIdx.y;
    const int colB = cs * CPB;

    const int srow  = tid >> 1;         // staging row 0..127
    const int skoff = (tid & 1) * 16;   // staging k offset 0/16

    // Per-lane esq values for the 16 (fr,reg) row slots (reused all ct).
    float er[16];
    #pragma unroll
    for (int fr = 0; fr < 4; fr++)
        #pragma unroll
        for (int rg = 0; rg < 4; rg++)
            er[fr * 4 + rg] = esq[row0 + wr * 64 + fr * 16 + q * 4 + rg];

    float best[16];
    int   bidx[16];
    #pragma unroll
    for (int i = 0; i < 16; i++) { best[i] = 3.4e38f; bidx[i] = 0; }

    for (int ct = 0; ct < NCT; ct++) {
        const int col0 = colB + ct * BC;
        f32x4 acc[4][4];
        #pragma unroll
        for (int i = 0; i < 4; i++)
            #pragma unroll
            for (int j = 0; j < 4; j++)
                acc[i][j] = (f32x4){0.f, 0.f, 0.f, 0.f};

        for (int kc = 0; kc < D_; kc += KC) {
            __syncthreads();   // protect LDS from previous chunk's readers
            // --- stage E and T fp16 chunks (no conversion) ---
            {
                const size_t eo = (size_t)(row0 + srow) * D_ + kc + skoff;
                half8 eh0 = *reinterpret_cast<const half8*>(Ehi_g + eo);
                half8 eh1 = *reinterpret_cast<const half8*>(Ehi_g + eo + 8);
                half8 el0 = *reinterpret_cast<const half8*>(Elo_g + eo);
                half8 el1 = *reinterpret_cast<const half8*>(Elo_g + eo + 8);
                const size_t to = (size_t)(col0 + srow) * D_ + kc + skoff;
                half8 th0 = *reinterpret_cast<const half8*>(Thi_g + to);
                half8 th1 = *reinterpret_cast<const half8*>(Thi_g + to + 8);
                half8 tl0 = *reinterpret_cast<const half8*>(Tlo_g + to);
                half8 tl1 = *reinterpret_cast<const half8*>(Tlo_g + to + 8);
                *reinterpret_cast<half8*>(&Ehi[srow][skoff])     = eh0;
                *reinterpret_cast<half8*>(&Ehi[srow][skoff + 8]) = eh1;
                *reinterpret_cast<half8*>(&Elo[srow][skoff])     = el0;
                *reinterpret_cast<half8*>(&Elo[srow][skoff + 8]) = el1;
                *reinterpret_cast<half8*>(&Thi[srow][skoff])     = th0;
                *reinterpret_cast<half8*>(&Thi[srow][skoff + 8]) = th1;
                *reinterpret_cast<half8*>(&Tlo[srow][skoff])     = tl0;
                *reinterpret_cast<half8*>(&Tlo[srow][skoff + 8]) = tl1;
            }
            __syncthreads();

            // --- frags: cache hi-frags, stream lo-frags through tmp ---
            // (identical MFMA order to round-6: hi*hi, hi*Tlo, Elo*hi)
            half8 ah[4], bh[4], tmp[4];
            #pragma unroll
            for (int f = 0; f < 4; f++)
                ah[f] = *reinterpret_cast<const half8*>(&Ehi[wr * 64 + f * 16 + cl][q * 8]);
            #pragma unroll
            for (int f = 0; f < 4; f++)
                bh[f] = *reinterpret_cast<const half8*>(&Thi[wc * 64 + f * 16 + cl][q * 8]);
            #pragma unroll
            for (int i = 0; i < 4; i++)
                #pragma unroll
                for (int j = 0; j < 4; j++)
                    acc[i][j] = __builtin_amdgcn_mfma_f32_16x16x32_f16(ah[i], bh[j], acc[i][j], 0, 0, 0);
            #pragma unroll
            for (int f = 0; f < 4; f++)
                tmp[f] = *reinterpret_cast<const half8*>(&Tlo[wc * 64 + f * 16 + cl][q * 8]);
            #pragma unroll
            for (int i = 0; i < 4; i++)
                #pragma unroll
                for (int j = 0; j < 4; j++)
                    acc[i][j] = __builtin_amdgcn_mfma_f32_16x16x32_f16(ah[i], tmp[j], acc[i][j], 0, 0, 0);
            #pragma unroll
            for (int f = 0; f < 4; f++)
                tmp[f] = *reinterpret_cast<const half8*>(&Elo[wr * 64 + f * 16 + cl][q * 8]);
            #pragma unroll
            for (int i = 0; i < 4; i++)
                #pragma unroll
                for (int j = 0; j < 4; j++)
                    acc[i][j] = __builtin_amdgcn_mfma_f32_16x16x32_f16(tmp[i], bh[j], acc[i][j], 0, 0, 0);
        }

        // Epilogue: d2 = fl(fl(er - acc*2^-16) + tc); running argmin.
        #pragma unroll
        for (int fc = 0; fc < 4; fc++) {
            const int col = col0 + wc * 64 + fc * 16 + cl;
            const float tc = tsq[col];
            #pragma unroll
            for (int fr = 0; fr < 4; fr++)
                #pragma unroll
                for (int rg = 0; rg < 4; rg++) {
                    const float c2 = acc[fr][fc][rg] * INV2;  // exact scale
                    const float d1 = __fsub_rn(er[fr * 4 + rg], c2);
                    const float d2 = __fadd_rn(d1, tc);
                    const int s = fr * 4 + rg;
                    if (d2 < best[s]) { best[s] = d2; bidx[s] = col; }
                }
        }
    }

    // Cross-lane reduce within each 16-lane quarter (same rows, diff cols).
    #pragma unroll
    for (int s = 0; s < 16; s++) {
        float v = best[s]; int i = bidx[s];
        #pragma unroll
        for (int off = 1; off < 16; off <<= 1) {
            float ov = __shfl_xor(v, off, 64);
            int   oi = __shfl_xor(i, off, 64);
            if (ov < v || (ov == v && oi < i)) { v = ov; i = oi; }
        }
        if (cl == 0) {
            const int row = row0 + wr * 64 + (s >> 2) * 16 + q * 4 + (s & 3);
            part[(size_t)row * NPART + cs * 2 + wc] = make_float2(v, __int_as_float(i));
        }
    }
}

// ---------------------------------------------------------------------------
// Kernel 3: reduce NPART partials per row (min value, min index on ties),
// gather quant = templat[idx] (bitwise copy), write zidx as float.
// ---------------------------------------------------------------------------
__global__ void gather_kernel(const float* __restrict__ T, const float2* __restrict__ part,
                              float* __restrict__ quant, float* __restrict__ zout) {
    int gt = blockIdx.x * blockDim.x + threadIdx.x;
    int w = gt >> 6, lane = gt & 63;
    if (w >= ROWS) return;
    float2 p = part[(size_t)w * NPART];
    float v = p.x; int idx = __float_as_int(p.y);
    #pragma unroll
    for (int c = 1; c < NPART; c++) {
        float2 q = part[(size_t)w * NPART + c];
        int qi = __float_as_int(q.y);
        if (q.x < v || (q.x == v && qi < idx)) { v = q.x; idx = qi; }
    }
    float4 t = *reinterpret_cast<const float4*>(T + (size_t)idx * D_ + lane * 4);
    *reinterpret_cast<float4*>(quant + (size_t)w * D_ + lane * 4) = t;
    if (lane == 0) zout[w] = (float)idx;
}

// ---------------------------------------------------------------------------
extern "C" void kernel_launch(void* const* d_in, const int* in_sizes, int n_in,
                              void* d_out, int out_size, void* d_ws, size_t ws_size,
                              hipStream_t stream) {
    const float* E = (const float*)d_in[0];   // encode  (B,N,D)
    const float* T = (const float*)d_in[1];   // templat (M,D)
    float* quant = (float*)d_out;                        // (B,N,D) fp32
    float* zout  = quant + (size_t)ROWS * D_;            // (B,N) idx as fp32

    // ws layout (floats): esq[ROWS], tsq[M], part[ROWS*NPART*2], then fp16
    // arrays Ehi/Elo[ROWS*D], Thi/Tlo[M*D]. Total ~23 MB.
    float* esq   = (float*)d_ws;
    float* tsq   = esq + ROWS;
    float2* part = (float2*)(tsq + M_);
    _Float16* Ehi = (_Float16*)(part + (size_t)ROWS * NPART);
    _Float16* Elo = Ehi + (size_t)ROWS * D_;
    _Float16* Thi = Elo + (size_t)ROWS * D_;
    _Float16* Tlo = Thi + (size_t)M_ * D_;

    hipLaunchKernelGGL(split_kernel, dim3((ROWS + M_) * 32 / 256), dim3(256), 0, stream,
                       E, T, Ehi, Elo, Thi, Tlo);
    hipLaunchKernelGGL(rowsq_kernel, dim3((ROWS + M_) * 16 / 256), dim3(256), 0, stream, E, T, esq, tsq);
    hipLaunchKernelGGL(score_kernel, dim3(ROWS / BR, CS), dim3(256), 0, stream,
                       Ehi, Elo, Thi, Tlo, esq, tsq, part);
    hipLaunchKernelGGL(gather_kernel, dim3(ROWS * 64 / 256), dim3(256), 0, stream, T, part, quant, zout);
}